// Round 7
// baseline (128.603 us; speedup 1.0000x reference)
//
#include <hip/hip_runtime.h>
#include <hip/hip_bf16.h>
#include <stdint.h>

// Problem constants (CompletePatchReadout): B=64,T=12,P=128,F=128,H=12,MAXC=48
namespace {
constexpr int kB = 64;
constexpr int kT = 12;
constexpr int kP = 128;
constexpr int kF = 128;
constexpr int kD = kT * kF;              // 1536
constexpr int kMAXC = 48;
constexpr int kH = 12;
constexpr int kNC = kMAXC * kH;          // 576 output cols per patch
constexpr int kKStep = 64;               // half a t-chunk per K step (VGPR diet)
constexpr int kSteps = kD / kKStep;      // 24
constexpr int kCTile = 96;               // cols per block
constexpr int kCBlocks = kNC / kCTile;   // 6
constexpr int kGrid = kP * kCBlocks;     // 768 (divisible by 8 XCDs)
constexpr int kNodesPerBlk = kCTile / kH;     // 8
constexpr int kNodeFloats = kB * kH;          // 768 floats = 3 KB per node
}

typedef __attribute__((ext_vector_type(8))) short short8;   // 8 bf16 (4 VGPR)
typedef __attribute__((ext_vector_type(4))) float f32x4;    // MFMA acc / vec IO

__device__ __forceinline__ uint16_t bf16_rne(float f) {
    uint32_t u = __builtin_bit_cast(uint32_t, f);
    u += 0x7FFFu + ((u >> 16) & 1u);     // round-to-nearest-even
    return (uint16_t)(u >> 16);
}

// LDS tile rows are 128 B (64 bf16). Without swizzle, 16 lanes reading the
// same 16-B k-slot of 16 consecutive rows (stride 128 B = 32 banks) all hit
// the same banks -> 16-way conflict. XOR byte-bits 4..6 with row&7 spreads
// them over 8 slots (residual 2-way on b128 is near-free, m136).
__device__ __forceinline__ int swz(int row, int byteoff) {
    return row * 128 + (byteoff ^ ((row & 7) << 4));
}

// Barrier WITHOUT vmcnt drain: prefetch global loads (register-targeted) stay
// in flight across it. lgkmcnt(0) publishes this wave's ds_writes / retires
// its ds_reads; s_barrier syncs the block. __syncthreads would emit
// s_waitcnt vmcnt(0) and kill the cross-step prefetch (m97 stall).
__device__ __forceinline__ void sync_lds() {
    asm volatile("s_waitcnt lgkmcnt(0)" ::: "memory");
    __builtin_amdgcn_s_barrier();
    asm volatile("" ::: "memory");
}

__global__ __launch_bounds__(256, 5)   // 5 blocks/CU: VGPR<=~102, LDS 24KB*5=120KB
void cpr_kernel(const float* __restrict__ x, const float* __restrict__ W,
                const float* __restrict__ bias, const int* __restrict__ node_map,
                float* __restrict__ out, int n_nodes) {
    __shared__ char lds[24 * 1024];          // tiles 20 KB; epilogue image 24 KB
    char* Xs = lds;                          // [64 b][64 k] bf16, swizzled (8 KB)
    char* Ws = lds + 64 * 128;               // [96 c][64 k] bf16 transposed (12 KB)

    // XCD-chunked swizzle: hw block i runs on XCD i%8; give XCD j the
    // contiguous work range [j*96, (j+1)*96) so all 6 cb-blocks of a patch
    // (and 16 consecutive patches) share one L2. Bijective: 768 % 8 == 0.
    const int hw   = blockIdx.x;
    const int work = (hw & 7) * (kGrid / 8) + (hw >> 3);
    const int p    = work / kCBlocks;
    const int cb   = work % kCBlocks;

    const int tid  = threadIdx.x;
    const int lane = tid & 63;
    const int wave = tid >> 6;
    const int wr = wave >> 1;    // wave M index: rows 32*wr..
    const int wc = wave & 1;     // wave N index: cols 48*wc..
    const int l15 = lane & 15;
    const int l4  = lane >> 4;

    // ---- hoisted loop-invariant per-thread addressing ----
    // (removes per-step %96 magic-mul chains + re-derived LDS addrs: less
    //  staging VALU -> faster issue burst, lower transient reg churn)
    uint32_t xoff[4], xlds[4];               // X: global byte off, LDS write addr
    #pragma unroll
    for (int i = 0; i < 4; ++i) {
        int q  = tid + 256 * i;   // 1024 float4 tasks
        int bi = q >> 4;          // 0..63
        int f4 = q & 15;          // 0..15
        xoff[i] = (uint32_t)(((long)bi * (kT * kP * kF) + f4 * 4) * 4);
        xlds[i] = (uint32_t)swz(bi, f4 * 8);
    }
    uint32_t woff[3], wlds[3];               // W: global byte off, LDS write addr
    #pragma unroll
    for (int i = 0; i < 3; ++i) {
        int q   = tid + 256 * i;  // 768 tasks = 96 c x 8 octets
        int c   = q % 96;
        int oct = q / 96;         // d-octet 0..7
        woff[i] = (uint32_t)(((long)(oct * 8) * kNC + c) * 4);
        wlds[i] = (uint32_t)swz(c, oct * 16);
    }

    f32x4 acc[2][3];
    #pragma unroll
    for (int mi = 0; mi < 2; ++mi)
        #pragma unroll
        for (int ni = 0; ni < 3; ++ni)
            acc[mi][ni] = (f32x4){0.f, 0.f, 0.f, 0.f};

    // ---- cross-step register prefetch (T14 async-STAGE split) ----
    f32x4 xg[4];     // 16 VGPR: X tile, coalesced float4 (L2-cached: 6x reuse)
    float wg[24];    // 24 VGPR: W tile, column-gather dwords (non-temporal:
                     //   W has ZERO reuse; nt keeps its 453MB stream from
                     //   evicting the 6x-reused X working set out of L2)

    auto issue_loads = [&](int step) {
        const int t    = step >> 1;          // t-chunk 0..11
        const int half = step & 1;           // which 64-f half
        const char* xbase = (const char*)(x + ((long)t * kP + p) * kF + half * 64);
        #pragma unroll
        for (int i = 0; i < 4; ++i)
            xg[i] = *reinterpret_cast<const f32x4*>(xbase + xoff[i]);
        const char* wbase = (const char*)(W + ((long)p * kD + (long)step * kKStep) * kNC
                                            + cb * kCTile);
        #pragma unroll
        for (int i = 0; i < 3; ++i) {
            const char* src = wbase + woff[i];
            #pragma unroll
            for (int j = 0; j < 8; ++j)
                wg[i * 8 + j] = __builtin_nontemporal_load(
                    reinterpret_cast<const float*>(src + (long)j * kNC * 4));
        }
    };

    issue_loads(0);

    #pragma unroll 1
    for (int step = 0; step < kSteps; ++step) {
        // ---- cvt + ds_write the prefetched tile (waits on vmcnt here only)
        #pragma unroll
        for (int i = 0; i < 4; ++i) {
            f32x4 v = xg[i];
            uint32_t lo = (uint32_t)bf16_rne(v.x) | ((uint32_t)bf16_rne(v.y) << 16);
            uint32_t hi = (uint32_t)bf16_rne(v.z) | ((uint32_t)bf16_rne(v.w) << 16);
            *reinterpret_cast<uint2*>(Xs + xlds[i]) = make_uint2(lo, hi);
        }
        #pragma unroll
        for (int i = 0; i < 3; ++i) {
            uint4 pack;
            pack.x = (uint32_t)bf16_rne(wg[i*8+0]) | ((uint32_t)bf16_rne(wg[i*8+1]) << 16);
            pack.y = (uint32_t)bf16_rne(wg[i*8+2]) | ((uint32_t)bf16_rne(wg[i*8+3]) << 16);
            pack.z = (uint32_t)bf16_rne(wg[i*8+4]) | ((uint32_t)bf16_rne(wg[i*8+5]) << 16);
            pack.w = (uint32_t)bf16_rne(wg[i*8+6]) | ((uint32_t)bf16_rne(wg[i*8+7]) << 16);
            *reinterpret_cast<uint4*>(Ws + wlds[i]) = pack;
        }

        // ---- issue next step's loads NOW; they stay in flight across both
        // barriers and the MFMA phase (registers only, no LDS visibility).
        if (step + 1 < kSteps) issue_loads(step + 1);

        sync_lds();   // publish ds_writes; NO vmcnt drain

        // ---- MFMA: 2 k-substeps of 32, wave computes 32x48 (2x3 16x16 tiles)
        #pragma unroll
        for (int kk = 0; kk < 2; ++kk) {
            const int kbyte = kk * 64 + l4 * 16;  // k = kk*32 + 8*(l>>4) + j
            short8 afrag[2], bfrag[3];
            #pragma unroll
            for (int mi = 0; mi < 2; ++mi)
                afrag[mi] = *reinterpret_cast<const short8*>(
                    Xs + swz(wr * 32 + mi * 16 + l15, kbyte));
            #pragma unroll
            for (int ni = 0; ni < 3; ++ni)
                bfrag[ni] = *reinterpret_cast<const short8*>(
                    Ws + swz(wc * 48 + ni * 16 + l15, kbyte));
            #pragma unroll
            for (int mi = 0; mi < 2; ++mi)
                #pragma unroll
                for (int ni = 0; ni < 3; ++ni)
                    acc[mi][ni] = __builtin_amdgcn_mfma_f32_16x16x32_bf16(
                        afrag[mi], bfrag[ni], acc[mi][ni], 0, 0, 0);
        }

        sync_lds();   // ds_reads retired before next step overwrites LDS
    }

    // ==== epilogue: acc+bias -> dense LDS image -> coalesced float4 stores ====
    // Block output = 8 node-chunks of 3072 B, each CONTIGUOUS in out
    // (out idx = node*768 + brow*12 + h).
    float* ldsO = reinterpret_cast<float*>(lds);   // [8][64][12] f32 = 24 KB

    // C/D layout (m89): col = lane&15, row = (lane>>4)*4 + reg
    #pragma unroll
    for (int ni = 0; ni < 3; ++ni) {
        int c_local = wc * 48 + ni * 16 + l15;
        int n_loc = c_local / kH;          // 0..7
        int h     = c_local - n_loc * kH;
        float bv = bias[p * kNC + cb * kCTile + c_local];
        #pragma unroll
        for (int mi = 0; mi < 2; ++mi)
            #pragma unroll
            for (int r = 0; r < 4; ++r) {
                int brow = wr * 32 + mi * 16 + l4 * 4 + r;
                ldsO[(n_loc * kB + brow) * kH + h] = acc[mi][ni][r] + bv;
            }
    }
    sync_lds();

    const int nbase = p * kMAXC + cb * kNodesPerBlk;
    #pragma unroll
    for (int i = 0; i < 6; ++i) {
        int q = tid + 256 * i;             // 1536 float4 tasks
        int n_loc = q / (kNodeFloats / 4); // 192 float4 per node
        int rem   = q - n_loc * (kNodeFloats / 4);
        int node  = node_map[nbase + n_loc];
        if (node < n_nodes) {              // padding (node==N) skipped
            f32x4 v = *reinterpret_cast<const f32x4*>(ldsO + q * 4);
            __builtin_nontemporal_store(v,
                reinterpret_cast<f32x4*>(out + (long)node * kNodeFloats + rem * 4));
        }
    }
}

extern "C" void kernel_launch(void* const* d_in, const int* in_sizes, int n_in,
                              void* d_out, int out_size, void* d_ws, size_t ws_size,
                              hipStream_t stream) {
    const float* x        = (const float*)d_in[0];
    const float* W        = (const float*)d_in[1];
    const float* bias     = (const float*)d_in[2];
    const int*   node_map = (const int*)d_in[3];
    float* out = (float*)d_out;
    const int n_nodes = out_size / (kB * kH);   // 4356
    dim3 grid(kGrid);                           // 768 blocks
    dim3 block(256);
    hipLaunchKernelGGL(cpr_kernel, grid, block, 0, stream,
                       x, W, bias, node_map, out, n_nodes);
}

// Round 8
// 87.703 us; speedup vs baseline: 1.4664x; 1.4664x over previous
//
#include <hip/hip_runtime.h>
#include <hip/hip_bf16.h>
#include <stdint.h>

// Problem constants (CompletePatchReadout): B=64,T=12,P=128,F=128,H=12,MAXC=48
namespace {
constexpr int kB = 64;
constexpr int kT = 12;
constexpr int kP = 128;
constexpr int kF = 128;
constexpr int kD = kT * kF;              // 1536
constexpr int kMAXC = 48;
constexpr int kH = 12;
constexpr int kNC = kMAXC * kH;          // 576 output cols per patch
constexpr int kKStep = 64;               // half a t-chunk per K step (VGPR diet)
constexpr int kSteps = kD / kKStep;      // 24
constexpr int kCTile = 96;               // cols per block
constexpr int kCBlocks = kNC / kCTile;   // 6
constexpr int kGrid = kP * kCBlocks;     // 768 (divisible by 8 XCDs)
constexpr int kNodesPerBlk = kCTile / kH;     // 8
constexpr int kNodeFloats = kB * kH;          // 768 floats = 3 KB per node
}

typedef __attribute__((ext_vector_type(8))) short short8;   // 8 bf16 (4 VGPR)
typedef __attribute__((ext_vector_type(4))) float f32x4;    // MFMA acc / vec IO

__device__ __forceinline__ uint16_t bf16_rne(float f) {
    uint32_t u = __builtin_bit_cast(uint32_t, f);
    u += 0x7FFFu + ((u >> 16) & 1u);     // round-to-nearest-even
    return (uint16_t)(u >> 16);
}

// LDS tile rows are 128 B (64 bf16). Without swizzle, 16 lanes reading the
// same 16-B k-slot of 16 consecutive rows (stride 128 B = 32 banks) all hit
// the same banks -> 16-way conflict. XOR byte-bits 4..6 with row&7 spreads
// them over 8 slots (residual 2-way on b128 is near-free, m136).
__device__ __forceinline__ int swz(int row, int byteoff) {
    return row * 128 + (byteoff ^ ((row & 7) << 4));
}

// Barrier WITHOUT vmcnt drain: prefetch global loads (register-targeted) stay
// in flight across it. lgkmcnt(0) publishes this wave's ds_writes / retires
// its ds_reads; s_barrier syncs the block. __syncthreads would emit
// s_waitcnt vmcnt(0) and kill the cross-step prefetch (m97 stall).
__device__ __forceinline__ void sync_lds() {
    asm volatile("s_waitcnt lgkmcnt(0)" ::: "memory");
    __builtin_amdgcn_s_barrier();
    asm volatile("" ::: "memory");
}

// (256,4): R6-proven sweet spot. (256,5) spilled the prefetch regs -> 128us (R7).
__global__ __launch_bounds__(256, 4)
void cpr_kernel(const float* __restrict__ x, const float* __restrict__ W,
                const float* __restrict__ bias, const int* __restrict__ node_map,
                float* __restrict__ out, int n_nodes) {
    __shared__ char lds[24 * 1024];          // tiles 20 KB; epilogue image 24 KB
    char* Xs = lds;                          // [64 b][64 k] bf16, swizzled (8 KB)
    char* Ws = lds + 64 * 128;               // [96 c][64 k] bf16 transposed (12 KB)

    // XCD-chunked swizzle: hw block i runs on XCD i%8; give XCD j the
    // contiguous work range [j*96, (j+1)*96) so all 6 cb-blocks of a patch
    // (and 16 consecutive patches) share one L2. Bijective: 768 % 8 == 0.
    const int hw   = blockIdx.x;
    const int work = (hw & 7) * (kGrid / 8) + (hw >> 3);
    const int p    = work / kCBlocks;
    const int cb   = work % kCBlocks;

    const int tid  = threadIdx.x;
    const int lane = tid & 63;
    const int wave = tid >> 6;
    const int wr = wave >> 1;    // wave M index: rows 32*wr..
    const int wc = wave & 1;     // wave N index: cols 48*wc..
    const int l15 = lane & 15;
    const int l4  = lane >> 4;

    // ---- hoisted loop-invariant per-thread addressing ----
    // (removes per-step %96 magic-mul chains + re-derived LDS addrs: less
    //  staging VALU -> faster issue burst, lower transient reg churn)
    uint32_t xoff[4], xlds[4];               // X: global byte off, LDS write addr
    #pragma unroll
    for (int i = 0; i < 4; ++i) {
        int q  = tid + 256 * i;   // 1024 float4 tasks
        int bi = q >> 4;          // 0..63
        int f4 = q & 15;          // 0..15
        xoff[i] = (uint32_t)(((long)bi * (kT * kP * kF) + f4 * 4) * 4);
        xlds[i] = (uint32_t)swz(bi, f4 * 8);
    }
    uint32_t woff[3], wlds[3];               // W: global byte off, LDS write addr
    #pragma unroll
    for (int i = 0; i < 3; ++i) {
        int q   = tid + 256 * i;  // 768 tasks = 96 c x 8 octets
        int c   = q % 96;
        int oct = q / 96;         // d-octet 0..7
        woff[i] = (uint32_t)(((long)(oct * 8) * kNC + c) * 4);
        wlds[i] = (uint32_t)swz(c, oct * 16);
    }

    f32x4 acc[2][3];
    #pragma unroll
    for (int mi = 0; mi < 2; ++mi)
        #pragma unroll
        for (int ni = 0; ni < 3; ++ni)
            acc[mi][ni] = (f32x4){0.f, 0.f, 0.f, 0.f};

    // ---- cross-step register prefetch (T14 async-STAGE split) ----
    f32x4 xg[4];     // 16 VGPR: X tile, coalesced float4 (L2-cached: 6x reuse)
    float wg[24];    // 24 VGPR: W tile, column-gather dwords (non-temporal:
                     //   W has ZERO reuse; nt keeps its 453MB stream from
                     //   evicting the 6x-reused X working set out of L2)

    auto issue_loads = [&](int step) {
        const int t    = step >> 1;          // t-chunk 0..11
        const int half = step & 1;           // which 64-f half
        const char* xbase = (const char*)(x + ((long)t * kP + p) * kF + half * 64);
        #pragma unroll
        for (int i = 0; i < 4; ++i)
            xg[i] = *reinterpret_cast<const f32x4*>(xbase + xoff[i]);
        const char* wbase = (const char*)(W + ((long)p * kD + (long)step * kKStep) * kNC
                                            + cb * kCTile);
        #pragma unroll
        for (int i = 0; i < 3; ++i) {
            const char* src = wbase + woff[i];
            #pragma unroll
            for (int j = 0; j < 8; ++j)
                wg[i * 8 + j] = __builtin_nontemporal_load(
                    reinterpret_cast<const float*>(src + (long)j * kNC * 4));
        }
    };

    issue_loads(0);

    #pragma unroll 1
    for (int step = 0; step < kSteps; ++step) {
        // ---- cvt + ds_write the prefetched tile (waits on vmcnt here only)
        #pragma unroll
        for (int i = 0; i < 4; ++i) {
            f32x4 v = xg[i];
            uint32_t lo = (uint32_t)bf16_rne(v.x) | ((uint32_t)bf16_rne(v.y) << 16);
            uint32_t hi = (uint32_t)bf16_rne(v.z) | ((uint32_t)bf16_rne(v.w) << 16);
            *reinterpret_cast<uint2*>(Xs + xlds[i]) = make_uint2(lo, hi);
        }
        #pragma unroll
        for (int i = 0; i < 3; ++i) {
            uint4 pack;
            pack.x = (uint32_t)bf16_rne(wg[i*8+0]) | ((uint32_t)bf16_rne(wg[i*8+1]) << 16);
            pack.y = (uint32_t)bf16_rne(wg[i*8+2]) | ((uint32_t)bf16_rne(wg[i*8+3]) << 16);
            pack.z = (uint32_t)bf16_rne(wg[i*8+4]) | ((uint32_t)bf16_rne(wg[i*8+5]) << 16);
            pack.w = (uint32_t)bf16_rne(wg[i*8+6]) | ((uint32_t)bf16_rne(wg[i*8+7]) << 16);
            *reinterpret_cast<uint4*>(Ws + wlds[i]) = pack;
        }

        // ---- issue next step's loads NOW; they stay in flight across both
        // barriers and the MFMA phase (registers only, no LDS visibility).
        if (step + 1 < kSteps) issue_loads(step + 1);

        sync_lds();   // publish ds_writes; NO vmcnt drain

        // ---- MFMA: 2 k-substeps of 32, wave computes 32x48 (2x3 16x16 tiles)
        #pragma unroll
        for (int kk = 0; kk < 2; ++kk) {
            const int kbyte = kk * 64 + l4 * 16;  // k = kk*32 + 8*(l>>4) + j
            short8 afrag[2], bfrag[3];
            #pragma unroll
            for (int mi = 0; mi < 2; ++mi)
                afrag[mi] = *reinterpret_cast<const short8*>(
                    Xs + swz(wr * 32 + mi * 16 + l15, kbyte));
            #pragma unroll
            for (int ni = 0; ni < 3; ++ni)
                bfrag[ni] = *reinterpret_cast<const short8*>(
                    Ws + swz(wc * 48 + ni * 16 + l15, kbyte));
            #pragma unroll
            for (int mi = 0; mi < 2; ++mi)
                #pragma unroll
                for (int ni = 0; ni < 3; ++ni)
                    acc[mi][ni] = __builtin_amdgcn_mfma_f32_16x16x32_bf16(
                        afrag[mi], bfrag[ni], acc[mi][ni], 0, 0, 0);
        }

        sync_lds();   // ds_reads retired before next step overwrites LDS
    }

    // ==== epilogue: acc+bias -> dense LDS image -> coalesced float4 stores ====
    // Block output = 8 node-chunks of 3072 B, each CONTIGUOUS in out
    // (out idx = node*768 + brow*12 + h).
    float* ldsO = reinterpret_cast<float*>(lds);   // [8][64][12] f32 = 24 KB

    // C/D layout (m89): col = lane&15, row = (lane>>4)*4 + reg
    #pragma unroll
    for (int ni = 0; ni < 3; ++ni) {
        int c_local = wc * 48 + ni * 16 + l15;
        int n_loc = c_local / kH;          // 0..7
        int h     = c_local - n_loc * kH;
        float bv = bias[p * kNC + cb * kCTile + c_local];
        #pragma unroll
        for (int mi = 0; mi < 2; ++mi)
            #pragma unroll
            for (int r = 0; r < 4; ++r) {
                int brow = wr * 32 + mi * 16 + l4 * 4 + r;
                ldsO[(n_loc * kB + brow) * kH + h] = acc[mi][ni][r] + bv;
            }
    }
    sync_lds();

    const int nbase = p * kMAXC + cb * kNodesPerBlk;
    #pragma unroll
    for (int i = 0; i < 6; ++i) {
        int q = tid + 256 * i;             // 1536 float4 tasks
        int n_loc = q / (kNodeFloats / 4); // 192 float4 per node
        int rem   = q - n_loc * (kNodeFloats / 4);
        int node  = node_map[nbase + n_loc];
        if (node < n_nodes) {              // padding (node==N) skipped
            f32x4 v = *reinterpret_cast<const f32x4*>(ldsO + q * 4);
            __builtin_nontemporal_store(v,
                reinterpret_cast<f32x4*>(out + (long)node * kNodeFloats + rem * 4));
        }
    }
}

extern "C" void kernel_launch(void* const* d_in, const int* in_sizes, int n_in,
                              void* d_out, int out_size, void* d_ws, size_t ws_size,
                              hipStream_t stream) {
    const float* x        = (const float*)d_in[0];
    const float* W        = (const float*)d_in[1];
    const float* bias     = (const float*)d_in[2];
    const int*   node_map = (const int*)d_in[3];
    float* out = (float*)d_out;
    const int n_nodes = out_size / (kB * kH);   // 4356
    dim3 grid(kGrid);                           // 768 blocks
    dim3 block(256);
    hipLaunchKernelGGL(cpr_kernel, grid, block, 0, stream,
                       x, W, bias, node_map, out, n_nodes);
}

// Round 9
// 80.766 us; speedup vs baseline: 1.5923x; 1.0859x over previous
//
#include <hip/hip_runtime.h>
#include <hip/hip_bf16.h>
#include <stdint.h>

// Problem constants (CompletePatchReadout): B=64,T=12,P=128,F=128,H=12,MAXC=48
namespace {
constexpr int kB = 64;
constexpr int kT = 12;
constexpr int kP = 128;
constexpr int kF = 128;
constexpr int kD = kT * kF;              // 1536
constexpr int kMAXC = 48;
constexpr int kH = 12;
constexpr int kNC = kMAXC * kH;          // 576 output cols per patch
constexpr int kKStep = 64;               // half a t-chunk per K step (VGPR diet)
constexpr int kSteps = kD / kKStep;      // 24
constexpr int kCTile = 96;               // cols per block
constexpr int kCBlocks = kNC / kCTile;   // 6
constexpr int kGrid = kP * kCBlocks;     // 768 (divisible by 8 XCDs)
constexpr int kNodesPerBlk = kCTile / kH;     // 8
constexpr int kNodeFloats = kB * kH;          // 768 floats = 3 KB per node
}

typedef __attribute__((ext_vector_type(8))) short short8;   // 8 bf16 (4 VGPR)
typedef __attribute__((ext_vector_type(4))) float f32x4;    // MFMA acc / vec IO

__device__ __forceinline__ uint16_t bf16_rne(float f) {
    uint32_t u = __builtin_bit_cast(uint32_t, f);
    u += 0x7FFFu + ((u >> 16) & 1u);     // round-to-nearest-even
    return (uint16_t)(u >> 16);
}

// LDS tile rows are 128 B (64 bf16). Without swizzle, 16 lanes reading the
// same 16-B k-slot of 16 consecutive rows (stride 128 B = 32 banks) all hit
// the same banks -> 16-way conflict. XOR byte-bits 4..6 with row&7 spreads
// them over 8 slots (residual 2-way on b128 is near-free, m136).
__device__ __forceinline__ int swz(int row, int byteoff) {
    return row * 128 + (byteoff ^ ((row & 7) << 4));
}

// Barrier WITHOUT vmcnt drain: prefetch global loads (register-targeted) stay
// in flight across it. lgkmcnt(0) publishes this wave's ds_writes / retires
// its ds_reads; s_barrier syncs the block. __syncthreads would emit
// s_waitcnt vmcnt(0) and kill the cross-step prefetch (m97 stall).
__device__ __forceinline__ void sync_lds() {
    asm volatile("s_waitcnt lgkmcnt(0)" ::: "memory");
    __builtin_amdgcn_s_barrier();
    asm volatile("" ::: "memory");
}

// (256,4): R6-proven sweet spot. (256,5) spilled the prefetch regs -> 128us (R7).
__global__ __launch_bounds__(256, 4)
void cpr_kernel(const float* __restrict__ x, const float* __restrict__ W,
                const float* __restrict__ bias, const int* __restrict__ node_map,
                float* __restrict__ out, int n_nodes) {
    __shared__ char lds[24 * 1024];          // tiles 20 KB; epilogue image 24 KB
    char* Xs = lds;                          // [64 b][64 k] bf16, swizzled (8 KB)
    char* Ws = lds + 64 * 128;               // [96 c][64 k] bf16 transposed (12 KB)

    // XCD-chunked swizzle: hw block i runs on XCD i%8; give XCD j the
    // contiguous work range [j*96, (j+1)*96) so all 6 cb-blocks of a patch
    // (and 16 consecutive patches) share one L2. Bijective: 768 % 8 == 0.
    const int hw   = blockIdx.x;
    const int work = (hw & 7) * (kGrid / 8) + (hw >> 3);
    const int p    = work / kCBlocks;
    const int cb   = work % kCBlocks;

    // ---- dead-work elimination (H8) ----
    // Padding nodes (node_map == N) are a CONTIGUOUS TAIL per patch; their
    // outputs are discarded by the reference. If this block's FIRST node is
    // padding, all 8 are -> whole block is dead work: exit (uniform branch).
    const int nbase = p * kMAXC + cb * kNodesPerBlk;
    if (node_map[nbase] == n_nodes) return;

    const int tid  = threadIdx.x;
    const int lane = tid & 63;
    const int wave = tid >> 6;
    const int wr = wave >> 1;    // wave M index: rows 32*wr..
    const int wc = wave & 1;     // wave N index: cols 48*wc..
    const int l15 = lane & 15;
    const int l4  = lane >> 4;

    // ---- hoisted loop-invariant per-thread addressing ----
    uint32_t xoff[4], xlds[4];               // X: global byte off, LDS write addr
    #pragma unroll
    for (int i = 0; i < 4; ++i) {
        int q  = tid + 256 * i;   // 1024 float4 tasks
        int bi = q >> 4;          // 0..63
        int f4 = q & 15;          // 0..15
        xoff[i] = (uint32_t)(((long)bi * (kT * kP * kF) + f4 * 4) * 4);
        xlds[i] = (uint32_t)swz(bi, f4 * 8);
    }
    uint32_t woff[3], wlds[3];               // W: global byte off, LDS write addr
    bool     wuse[3];                        // column belongs to a USEFUL node?
    #pragma unroll
    for (int i = 0; i < 3; ++i) {
        int q   = tid + 256 * i;  // 768 tasks = 96 c x 8 octets
        int c   = q % 96;
        int oct = q / 96;         // d-octet 0..7
        woff[i] = (uint32_t)(((long)(oct * 8) * kNC + c) * 4);
        wlds[i] = (uint32_t)swz(c, oct * 16);
        // lanes gathering a padding node's column skip their loads entirely:
        // ~29% of W (dead tail columns) never leaves HBM.
        wuse[i] = node_map[nbase + c / kH] != n_nodes;
    }

    f32x4 acc[2][3];
    #pragma unroll
    for (int mi = 0; mi < 2; ++mi)
        #pragma unroll
        for (int ni = 0; ni < 3; ++ni)
            acc[mi][ni] = (f32x4){0.f, 0.f, 0.f, 0.f};

    // ---- cross-step register prefetch (T14 async-STAGE split) ----
    f32x4 xg[4];         // 16 VGPR: X tile, coalesced float4 (L2: 6x reuse)
    float wg[24] = {};   // 24 VGPR: W column-gather (zero-init: padding lanes
                         //   never load; their acc columns are discarded)

    auto issue_loads = [&](int step) {
        const int t    = step >> 1;          // t-chunk 0..11
        const int half = step & 1;           // which 64-f half
        const char* xbase = (const char*)(x + ((long)t * kP + p) * kF + half * 64);
        #pragma unroll
        for (int i = 0; i < 4; ++i)
            xg[i] = *reinterpret_cast<const f32x4*>(xbase + xoff[i]);
        const char* wbase = (const char*)(W + ((long)p * kD + (long)step * kKStep) * kNC
                                            + cb * kCTile);
        #pragma unroll
        for (int i = 0; i < 3; ++i) {
            if (wuse[i]) {   // exec-masked: padding lanes fetch nothing
                const char* src = wbase + woff[i];
                #pragma unroll
                for (int j = 0; j < 8; ++j)
                    wg[i * 8 + j] = __builtin_nontemporal_load(
                        reinterpret_cast<const float*>(src + (long)j * kNC * 4));
            }
        }
    };

    issue_loads(0);

    #pragma unroll 1
    for (int step = 0; step < kSteps; ++step) {
        // ---- cvt + ds_write the prefetched tile (waits on vmcnt here only)
        #pragma unroll
        for (int i = 0; i < 4; ++i) {
            f32x4 v = xg[i];
            uint32_t lo = (uint32_t)bf16_rne(v.x) | ((uint32_t)bf16_rne(v.y) << 16);
            uint32_t hi = (uint32_t)bf16_rne(v.z) | ((uint32_t)bf16_rne(v.w) << 16);
            *reinterpret_cast<uint2*>(Xs + xlds[i]) = make_uint2(lo, hi);
        }
        #pragma unroll
        for (int i = 0; i < 3; ++i) {
            uint4 pack;
            pack.x = (uint32_t)bf16_rne(wg[i*8+0]) | ((uint32_t)bf16_rne(wg[i*8+1]) << 16);
            pack.y = (uint32_t)bf16_rne(wg[i*8+2]) | ((uint32_t)bf16_rne(wg[i*8+3]) << 16);
            pack.z = (uint32_t)bf16_rne(wg[i*8+4]) | ((uint32_t)bf16_rne(wg[i*8+5]) << 16);
            pack.w = (uint32_t)bf16_rne(wg[i*8+6]) | ((uint32_t)bf16_rne(wg[i*8+7]) << 16);
            *reinterpret_cast<uint4*>(Ws + wlds[i]) = pack;
        }

        // ---- issue next step's loads NOW; they stay in flight across both
        // barriers and the MFMA phase (registers only, no LDS visibility).
        if (step + 1 < kSteps) issue_loads(step + 1);

        sync_lds();   // publish ds_writes; NO vmcnt drain

        // ---- MFMA: 2 k-substeps of 32, wave computes 32x48 (2x3 16x16 tiles)
        #pragma unroll
        for (int kk = 0; kk < 2; ++kk) {
            const int kbyte = kk * 64 + l4 * 16;  // k = kk*32 + 8*(l>>4) + j
            short8 afrag[2], bfrag[3];
            #pragma unroll
            for (int mi = 0; mi < 2; ++mi)
                afrag[mi] = *reinterpret_cast<const short8*>(
                    Xs + swz(wr * 32 + mi * 16 + l15, kbyte));
            #pragma unroll
            for (int ni = 0; ni < 3; ++ni)
                bfrag[ni] = *reinterpret_cast<const short8*>(
                    Ws + swz(wc * 48 + ni * 16 + l15, kbyte));
            #pragma unroll
            for (int mi = 0; mi < 2; ++mi)
                #pragma unroll
                for (int ni = 0; ni < 3; ++ni)
                    acc[mi][ni] = __builtin_amdgcn_mfma_f32_16x16x32_bf16(
                        afrag[mi], bfrag[ni], acc[mi][ni], 0, 0, 0);
        }

        sync_lds();   // ds_reads retired before next step overwrites LDS
    }

    // ==== epilogue: acc+bias -> dense LDS image -> coalesced float4 stores ====
    // Block output = 8 node-chunks of 3072 B, each CONTIGUOUS in out
    // (out idx = node*768 + brow*12 + h).
    float* ldsO = reinterpret_cast<float*>(lds);   // [8][64][12] f32 = 24 KB

    // C/D layout (m89): col = lane&15, row = (lane>>4)*4 + reg
    #pragma unroll
    for (int ni = 0; ni < 3; ++ni) {
        int c_local = wc * 48 + ni * 16 + l15;
        int n_loc = c_local / kH;          // 0..7
        int h     = c_local - n_loc * kH;
        float bv = bias[p * kNC + cb * kCTile + c_local];
        #pragma unroll
        for (int mi = 0; mi < 2; ++mi)
            #pragma unroll
            for (int r = 0; r < 4; ++r) {
                int brow = wr * 32 + mi * 16 + l4 * 4 + r;
                ldsO[(n_loc * kB + brow) * kH + h] = acc[mi][ni][r] + bv;
            }
    }
    sync_lds();

    #pragma unroll
    for (int i = 0; i < 6; ++i) {
        int q = tid + 256 * i;             // 1536 float4 tasks
        int n_loc = q / (kNodeFloats / 4); // 192 float4 per node
        int rem   = q - n_loc * (kNodeFloats / 4);
        int node  = node_map[nbase + n_loc];
        if (node < n_nodes) {              // padding (node==N) skipped
            f32x4 v = *reinterpret_cast<const f32x4*>(ldsO + q * 4);
            __builtin_nontemporal_store(v,
                reinterpret_cast<f32x4*>(out + (long)node * kNodeFloats + rem * 4));
        }
    }
}

extern "C" void kernel_launch(void* const* d_in, const int* in_sizes, int n_in,
                              void* d_out, int out_size, void* d_ws, size_t ws_size,
                              hipStream_t stream) {
    const float* x        = (const float*)d_in[0];
    const float* W        = (const float*)d_in[1];
    const float* bias     = (const float*)d_in[2];
    const int*   node_map = (const int*)d_in[3];
    float* out = (float*)d_out;
    const int n_nodes = out_size / (kB * kH);   // 4356
    dim3 grid(kGrid);                           // 768 blocks
    dim3 block(256);
    hipLaunchKernelGGL(cpr_kernel, grid, block, 0, stream,
                       x, W, bias, node_map, out, n_nodes);
}